// Round 8
// baseline (240.835 us; speedup 1.0000x reference)
//
#include <hip/hip_runtime.h>
#include <cstdint>
#include <cstddef>

// 20-qubit statevector sim, ONE kernel: 6 passes (2 per layer) with fence-free
// flag grid barriers, 512 blocks x 256 threads.
//
// R6 post-mortem: per-block __threadfence (agent release/acquire) emits
// buffer_wbl2 + buffer_inv (full L2 scan, serialized per XCD) -> ~100us per
// grid barrier. R8 fix: ALL cross-block psi traffic uses RELAXED AGENT-scope
// atomics (8B float2 granules -> global_{load,store}_dwordx2 sc1, coherent at
// the LLC). Barriers then need NO cache maintenance: __syncthreads() drains
// vmcnt in every wave (sc1 stores ack'd at LLC), thread0 sets this block's
// flag (relaxed agent), one wave polls all 512 flags (relaxed agent — R6
// proved this poll pattern is cheap: 22 MB total), __syncthreads().
//
// Algorithm (verified passing since R5):
// Pass S1(k): U3 q0..q10 + CU3 (0,1)..(9,10); tile bits 0..10 = q0..q10,
//   block bits 11..19 = q11..q19.
// Pass S2(k): U3 q11..q19 + CU3 (10,11)..(19,0); tile = (q10,q11..q19,q0),
//   block = (q1..q9).
// 5 phases/pass, register window always tile bits (0,1,2); tile rotates down
// by 2 between phases (L' = (L>>2)|((L&3)<<9)), LDS double-buffered, b128.
// After 4 rotations regs are rotated by 8: m=(w8,w9,w10), t=(w0..w7);
// cross-pass store: f4 = b + 512*t0 + 1024*(t>>1) + 2^17*m0 + 2^18*m1.
// Final pass: x=(0.8*tanh(0.1*2^19*|a|^2))^0.3, block sums -> barrier ->
// mean -> bit-reversed scatter of x-mean to out (normal stores; dispatch end
// publishes them to the host).

#define NB 512
#define NT 256
#define MAGIC 0x13572468u
#define PHYS(L) ((L) + 2u * ((L) >> 4))

using u64 = unsigned long long;

__device__ __forceinline__ void st_amp(u64* p, unsigned idx, float2 v) {
  union { float2 f; u64 u; } c; c.f = v;
  __hip_atomic_store(p + idx, c.u, __ATOMIC_RELAXED, __HIP_MEMORY_SCOPE_AGENT);
}
__device__ __forceinline__ float2 ld_amp(u64* p, unsigned idx) {
  union { float2 f; u64 u; } c;
  c.u = __hip_atomic_load(p + idx, __ATOMIC_RELAXED, __HIP_MEMORY_SCOPE_AGENT);
  return c.f;
}

__device__ __forceinline__ float2 cmadd2(float2 m0, float2 a0, float2 m1, float2 a1) {
  float2 r;
  r.x = m0.x * a0.x - m0.y * a0.y + m1.x * a1.x - m1.y * a1.y;
  r.y = m0.x * a0.y + m0.y * a0.x + m1.x * a1.y + m1.y * a1.x;
  return r;
}

template <int BIT>
__device__ __forceinline__ void applyU3(float2* v, const float2* m) {
  float2 m00 = m[0], m01 = m[1], m10 = m[2], m11 = m[3];
#pragma unroll
  for (int j = 0; j < 8; j++)
    if (!((j >> BIT) & 1)) {
      int j1 = j | (1 << BIT);
      float2 a0 = v[j], a1 = v[j1];
      v[j] = cmadd2(m00, a0, m01, a1);
      v[j1] = cmadd2(m10, a0, m11, a1);
    }
}

template <int C, int T>
__device__ __forceinline__ void applyCU3(float2* v, const float2* m) {
  float2 u00 = m[0], u01 = m[1], u10 = m[2], u11 = m[3];
#pragma unroll
  for (int j = 0; j < 8; j++)
    if (((j >> C) & 1) && !((j >> T) & 1)) {
      int j1 = j | (1 << T);
      float2 a0 = v[j], a1 = v[j1];
      v[j] = cmadd2(u00, a0, u01, a1);
      v[j1] = cmadd2(u10, a0, u11, a1);
    }
}

template <int U0, int U1, int U2, int C01, int C12>
__device__ __forceinline__ void phase(float2* v, const float2* MU, const float2* MC) {
  if (U0 >= 0) applyU3<0>(v, MU + 4 * (U0 < 0 ? 0 : U0));
  if (U1 >= 0) applyU3<1>(v, MU + 4 * (U1 < 0 ? 0 : U1));
  if (U2 >= 0) applyU3<2>(v, MU + 4 * (U2 < 0 ? 0 : U2));
  if (C01 >= 0) applyCU3<0, 1>(v, MC + 4 * (C01 < 0 ? 0 : C01));
  if (C12 >= 0) applyCU3<1, 2>(v, MC + 4 * (C12 < 0 ? 0 : C12));
}

__device__ __forceinline__ void rot_store(float2* lds, unsigned t, const float2* v) {
#pragma unroll
  for (int q = 0; q < 4; q++) {
    unsigned Lp = 2u * t + 512u * q;
    *(float4*)&lds[PHYS(Lp)] = make_float4(v[q].x, v[q].y, v[q + 4].x, v[q + 4].y);
  }
}

__device__ __forceinline__ void rot_load(const float2* lds, unsigned t, float2* v) {
  const float4* p = (const float4*)&lds[PHYS(8u * t)];
#pragma unroll
  for (int i = 0; i < 4; i++) {
    float4 f = p[i];
    v[2 * i] = make_float2(f.x, f.y);
    v[2 * i + 1] = make_float2(f.z, f.w);
  }
}

__device__ __forceinline__ float xval(float2 a) {
  float p = a.x * a.x + a.y * a.y;
  return powf(0.8f * tanhf(52428.8f * p), 0.3f);
}

__device__ __forceinline__ void mat_from(const float* s, float2* m) {
  float st, ct, sl, cl, sp, cp, spl, cpl;
  sincosf(0.5f * s[0], &st, &ct);
  sincosf(s[2], &sl, &cl);
  sincosf(s[1], &sp, &cp);
  sincosf(s[1] + s[2], &spl, &cpl);
  m[0] = make_float2(ct, 0.f);
  m[1] = make_float2(-cl * st, -sl * st);
  m[2] = make_float2(cp * st, sp * st);
  m[3] = make_float2(cpl * ct, spl * ct);
}

// Fence-free grid barrier (see header comment).
__device__ __forceinline__ void gridbar(unsigned* flags, int slot, unsigned b,
                                        unsigned t) {
  __syncthreads();  // compiler emits s_waitcnt vmcnt(0) in EVERY wave first
  unsigned* base = flags + slot * NB;
  if (t == 0)
    __hip_atomic_store(base + b, MAGIC, __ATOMIC_RELAXED, __HIP_MEMORY_SCOPE_AGENT);
  if (t < 64) {
    unsigned* p = base + 8 * t;
    int guard = 0;
    for (;;) {
      unsigned ok = 1u;
#pragma unroll
      for (int i = 0; i < 8; i++)
        ok &= (__hip_atomic_load(p + i, __ATOMIC_RELAXED,
                                 __HIP_MEMORY_SCOPE_AGENT) == MAGIC);
      if (__all((int)ok)) break;
      if (++guard > (1 << 18)) break;  // fail loud, never hang
      __builtin_amdgcn_s_sleep(8);
    }
  }
  __syncthreads();
}

// TYPE 0 = S1, 1 = S2; INIT synthesizes |0..0>; FINAL does readout.
template <int TYPE, int INIT, int FINAL>
__device__ __forceinline__ void do_pass(int k, u64* in, u64* outPsi,
                                        float2* A, float2* B, const float2* Mall,
                                        float* red, unsigned t, unsigned b,
                                        float* sumArr, unsigned* flags,
                                        float* out) {
  const float2* MU = Mall + k * 80;
  const float2* MC = Mall + 240 + k * 80;

  float2 v[8];
  if (INIT) {
#pragma unroll
    for (int j = 0; j < 8; j++) v[j] = make_float2(0.f, 0.f);
    if (b == 0 && t == 0) v[0] = make_float2(1.f, 0.f);
  } else {
    unsigned base = (b << 11) + 8u * t;
#pragma unroll
    for (int i = 0; i < 8; i++) v[i] = ld_amp(in, base + i);
  }

  if (TYPE == 0) phase<0, 1, 2, 0, 1>(v, MU, MC);      else phase<-1, 11, 12, 10, 11>(v, MU, MC);
  rot_store(A, t, v); __syncthreads(); rot_load(A, t, v);
  if (TYPE == 0) phase<-1, 3, 4, 2, 3>(v, MU, MC);     else phase<-1, 13, 14, 12, 13>(v, MU, MC);
  rot_store(B, t, v); __syncthreads(); rot_load(B, t, v);
  if (TYPE == 0) phase<-1, 5, 6, 4, 5>(v, MU, MC);     else phase<-1, 15, 16, 14, 15>(v, MU, MC);
  rot_store(A, t, v); __syncthreads(); rot_load(A, t, v);
  if (TYPE == 0) phase<-1, 7, 8, 6, 7>(v, MU, MC);     else phase<-1, 17, 18, 16, 17>(v, MU, MC);
  rot_store(B, t, v); __syncthreads(); rot_load(B, t, v);
  if (TYPE == 0) phase<-1, 9, 10, 8, 9>(v, MU, MC);    else phase<-1, 19, -1, 18, 19>(v, MU, MC);

  if (!FINAL) {
    // float2 index B2 = 2*(b + (t0<<9) + ((t>>1)<<10)); pairs at +2^18 strides
    unsigned B2 = 2u * (b + ((t & 1u) << 9) + ((t >> 1) << 10));
    st_amp(outPsi, B2, v[0]);                st_amp(outPsi, B2 + 1, v[4]);
    st_amp(outPsi, B2 + (1u << 18), v[1]);   st_amp(outPsi, B2 + (1u << 18) + 1, v[5]);
    st_amp(outPsi, B2 + (1u << 19), v[2]);   st_amp(outPsi, B2 + (1u << 19) + 1, v[6]);
    st_amp(outPsi, B2 + (3u << 18), v[3]);   st_amp(outPsi, B2 + (3u << 18) + 1, v[7]);
  } else {
    // S2(2) end: m=(q18,q19,q0), t=(q10..q17), blk=(q1..q9).
    // Reference R (bit 19-q): R = m1 + 2*m0 + 4*rev8(t) + 1024*rev9(b) + 2^19*m2
    float xv[8];
    float s = 0.f;
#pragma unroll
    for (int m = 0; m < 8; m++) { xv[m] = xval(v[m]); s += xv[m]; }
#pragma unroll
    for (int o = 32; o > 0; o >>= 1) s += __shfl_down(s, o);
    if ((t & 63u) == 0) red[t >> 6] = s;
    __syncthreads();
    if (t == 0)
      __hip_atomic_store(&sumArr[b], red[0] + red[1] + red[2] + red[3],
                         __ATOMIC_RELAXED, __HIP_MEMORY_SCOPE_AGENT);
    gridbar(flags, 5, b, t);
    float s2 = __hip_atomic_load(&sumArr[2 * t], __ATOMIC_RELAXED,
                                 __HIP_MEMORY_SCOPE_AGENT) +
               __hip_atomic_load(&sumArr[2 * t + 1], __ATOMIC_RELAXED,
                                 __HIP_MEMORY_SCOPE_AGENT);
#pragma unroll
    for (int o = 32; o > 0; o >>= 1) s2 += __shfl_down(s2, o);
    __syncthreads();  // red reuse
    if ((t & 63u) == 0) red[t >> 6] = s2;
    __syncthreads();
    float mean = (red[0] + red[1] + red[2] + red[3]) * (1.f / 1048576.f);
    float4* o4 = (float4*)out;
    unsigned base = (__brev(t) >> 24) + ((__brev(b) >> 23) << 8);
    o4[base] = make_float4(xv[0] - mean, xv[2] - mean, xv[1] - mean, xv[3] - mean);
    o4[base + (1u << 17)] =
        make_float4(xv[4] - mean, xv[6] - mean, xv[5] - mean, xv[7] - mean);
  }
}

__global__ __launch_bounds__(NT) void qsim(const float* __restrict__ u3p,
                                           const float* __restrict__ cu3p,
                                           u64* __restrict__ psiA,
                                           u64* __restrict__ psiB,
                                           unsigned* __restrict__ flags,
                                           float* __restrict__ sumArr,
                                           float* __restrict__ out) {
  __shared__ float2 A[2304], B[2304];  // PHYS(2047)=2301
  __shared__ float2 Mall[480];         // 3 layers x (20 U3 + 20 CU3) x 4
  __shared__ float red[4];
  unsigned t = threadIdx.x, b = blockIdx.x;

  if (t < 60) mat_from(u3p + 3 * t, Mall + 4 * t);
  else if (t >= 64 && t < 124) mat_from(cu3p + 3 * (t - 64), Mall + 240 + 4 * (t - 64));
  __syncthreads();

  do_pass<0, 1, 0>(0, nullptr, psiB, A, B, Mall, red, t, b, sumArr, flags, out);
  gridbar(flags, 0, b, t);
  do_pass<1, 0, 0>(0, psiB, psiA, A, B, Mall, red, t, b, sumArr, flags, out);
  gridbar(flags, 1, b, t);
  do_pass<0, 0, 0>(1, psiA, psiB, A, B, Mall, red, t, b, sumArr, flags, out);
  gridbar(flags, 2, b, t);
  do_pass<1, 0, 0>(1, psiB, psiA, A, B, Mall, red, t, b, sumArr, flags, out);
  gridbar(flags, 3, b, t);
  do_pass<0, 0, 0>(2, psiA, psiB, A, B, Mall, red, t, b, sumArr, flags, out);
  gridbar(flags, 4, b, t);
  do_pass<1, 0, 1>(2, psiB, nullptr, A, B, Mall, red, t, b, sumArr, flags, out);
}

extern "C" void kernel_launch(void* const* d_in, const int* in_sizes, int n_in,
                              void* d_out, int out_size, void* d_ws, size_t ws_size,
                              hipStream_t stream) {
  const float* u3p = (const float*)d_in[0];
  const float* cu3p = (const float*)d_in[1];
  float* out = (float*)d_out;

  char* ws = (char*)d_ws;
  u64* psiA = (u64*)ws;                                         // 8 MB
  u64* psiB = (u64*)(ws + (size_t)8 * 1024 * 1024);             // 8 MB
  unsigned* flags = (unsigned*)(ws + (size_t)16 * 1024 * 1024); // 12 KB
  float* sumArr = (float*)(ws + (size_t)16 * 1024 * 1024 + 6 * NB * sizeof(unsigned));

  qsim<<<NB, NT, 0, stream>>>(u3p, cu3p, psiA, psiB, flags, sumArr, out);
}

// Round 9
// 190.224 us; speedup vs baseline: 1.2661x; 1.2661x over previous
//
#include <hip/hip_runtime.h>
#include <cstdint>
#include <cstddef>

// 20-qubit statevector sim, ONE kernel: 6 passes (2 per layer), fence-free
// flag grid barriers (R8-proven), 512 blocks x 256 threads.
//
// R8 post-mortem: cross-pass sc1 stores were 16B granules at 2KB stride ->
// 4x write amplification (WRITE_SIZE 168MB vs 44MB useful) -> HBM-bound.
// R9: new exchange layout. Per hop, in producer-chain labels (chain c0..c10 =
// this pass's window in ring order, d0..d8 = its external qubits):
//   G = c0 + 2*c10 + 4*c8 + 8*c9 + 16*(c1..c7) + 2^11*(d0..d8)   [float2 idx]
// Producer (regs j=(c8,c9,c10), lanes t=(c0..c7)) stores wave-dense: each
// lane-pair x 8 regs covers a full 128B line; wave covers 4KB.
// Consumer (next pass: window (c10,d0..d8,c0), block (c1..c9)) gathers
// 32B chunks (4 consecutive lanes coalesce; 16 chunks/instr at 16KB stride),
// scatters into LDS in tile order (2-way bank aliasing only = free), then
// the rotation-phase machinery runs as before.
// Mapping probe-verified for q0,q8,q10,q11,q18 and hop symmetry S1->S2->S1.
//
// Phases: window always tile bits (0,1,2); tile rotates down by 2 between
// phases via LDS A/B double buffer, all b128. After 4 rotations regs hold
// m=(w8,w9,w10), t=(w0..w7). Final pass: x=(0.8*tanh(0.1*2^19*p))^0.3,
// block sums -> barrier -> mean -> bit-reversed scatter of x-mean to out.

#define NB 512
#define NT 256
#define MAGIC 0x13572468u
#define PHYS(L) ((L) + 2u * ((L) >> 4))

using u64 = unsigned long long;

__device__ __forceinline__ void st_amp(u64* p, unsigned idx, float2 v) {
  union { float2 f; u64 u; } c; c.f = v;
  __hip_atomic_store(p + idx, c.u, __ATOMIC_RELAXED, __HIP_MEMORY_SCOPE_AGENT);
}
__device__ __forceinline__ float2 ld_amp(u64* p, unsigned idx) {
  union { float2 f; u64 u; } c;
  c.u = __hip_atomic_load(p + idx, __ATOMIC_RELAXED, __HIP_MEMORY_SCOPE_AGENT);
  return c.f;
}

__device__ __forceinline__ float2 cmadd2(float2 m0, float2 a0, float2 m1, float2 a1) {
  float2 r;
  r.x = m0.x * a0.x - m0.y * a0.y + m1.x * a1.x - m1.y * a1.y;
  r.y = m0.x * a0.y + m0.y * a0.x + m1.x * a1.y + m1.y * a1.x;
  return r;
}

template <int BIT>
__device__ __forceinline__ void applyU3(float2* v, const float2* m) {
  float2 m00 = m[0], m01 = m[1], m10 = m[2], m11 = m[3];
#pragma unroll
  for (int j = 0; j < 8; j++)
    if (!((j >> BIT) & 1)) {
      int j1 = j | (1 << BIT);
      float2 a0 = v[j], a1 = v[j1];
      v[j] = cmadd2(m00, a0, m01, a1);
      v[j1] = cmadd2(m10, a0, m11, a1);
    }
}

template <int C, int T>
__device__ __forceinline__ void applyCU3(float2* v, const float2* m) {
  float2 u00 = m[0], u01 = m[1], u10 = m[2], u11 = m[3];
#pragma unroll
  for (int j = 0; j < 8; j++)
    if (((j >> C) & 1) && !((j >> T) & 1)) {
      int j1 = j | (1 << T);
      float2 a0 = v[j], a1 = v[j1];
      v[j] = cmadd2(u00, a0, u01, a1);
      v[j1] = cmadd2(u10, a0, u11, a1);
    }
}

template <int U0, int U1, int U2, int C01, int C12>
__device__ __forceinline__ void phase(float2* v, const float2* MU, const float2* MC) {
  if (U0 >= 0) applyU3<0>(v, MU + 4 * (U0 < 0 ? 0 : U0));
  if (U1 >= 0) applyU3<1>(v, MU + 4 * (U1 < 0 ? 0 : U1));
  if (U2 >= 0) applyU3<2>(v, MU + 4 * (U2 < 0 ? 0 : U2));
  if (C01 >= 0) applyCU3<0, 1>(v, MC + 4 * (C01 < 0 ? 0 : C01));
  if (C12 >= 0) applyCU3<1, 2>(v, MC + 4 * (C12 < 0 ? 0 : C12));
}

__device__ __forceinline__ void rot_store(float2* lds, unsigned t, const float2* v) {
#pragma unroll
  for (int q = 0; q < 4; q++) {
    unsigned Lp = 2u * t + 512u * q;
    *(float4*)&lds[PHYS(Lp)] = make_float4(v[q].x, v[q].y, v[q + 4].x, v[q + 4].y);
  }
}

__device__ __forceinline__ void rot_load(const float2* lds, unsigned t, float2* v) {
  const float4* p = (const float4*)&lds[PHYS(8u * t)];
#pragma unroll
  for (int i = 0; i < 4; i++) {
    float4 f = p[i];
    v[2 * i] = make_float2(f.x, f.y);
    v[2 * i + 1] = make_float2(f.z, f.w);
  }
}

__device__ __forceinline__ float xval(float2 a) {
  float p = a.x * a.x + a.y * a.y;
  return powf(0.8f * tanhf(52428.8f * p), 0.3f);
}

__device__ __forceinline__ void mat_from(const float* s, float2* m) {
  float st, ct, sl, cl, sp, cp, spl, cpl;
  sincosf(0.5f * s[0], &st, &ct);
  sincosf(s[2], &sl, &cl);
  sincosf(s[1], &sp, &cp);
  sincosf(s[1] + s[2], &spl, &cpl);
  m[0] = make_float2(ct, 0.f);
  m[1] = make_float2(-cl * st, -sl * st);
  m[2] = make_float2(cp * st, sp * st);
  m[3] = make_float2(cpl * ct, spl * ct);
}

// Fence-free grid barrier (R8-proven).
__device__ __forceinline__ void gridbar(unsigned* flags, int slot, unsigned b,
                                        unsigned t) {
  __syncthreads();  // every wave drains vmcnt first (sc1 stores LLC-ack'd)
  unsigned* base = flags + slot * NB;
  if (t == 0)
    __hip_atomic_store(base + b, MAGIC, __ATOMIC_RELAXED, __HIP_MEMORY_SCOPE_AGENT);
  if (t < 64) {
    unsigned* p = base + 8 * t;
    int guard = 0;
    for (;;) {
      unsigned ok = 1u;
#pragma unroll
      for (int i = 0; i < 8; i++)
        ok &= (__hip_atomic_load(p + i, __ATOMIC_RELAXED,
                                 __HIP_MEMORY_SCOPE_AGENT) == MAGIC);
      if (__all((int)ok)) break;
      if (++guard > (1 << 18)) break;  // fail loud, never hang
      __builtin_amdgcn_s_sleep(8);
    }
  }
  __syncthreads();
}

// TYPE 0 = S1, 1 = S2; INIT synthesizes |0..0>; FINAL does readout.
template <int TYPE, int INIT, int FINAL>
__device__ __forceinline__ void do_pass(int k, u64* in, u64* outPsi,
                                        float2* A, float2* B, const float2* Mall,
                                        float* red, unsigned t, unsigned b,
                                        float* sumArr, unsigned* flags,
                                        float* out) {
  const float2* MU = Mall + k * 80;
  const float2* MC = Mall + 240 + k * 80;

  float2 v[8];
  if (INIT) {
#pragma unroll
    for (int j = 0; j < 8; j++) v[j] = make_float2(0.f, 0.f);
    if (b == 0 && t == 0) v[0] = make_float2(1.f, 0.f);
  } else {
    // Staged gather. Consumer block b = (c1..c9) of the PREVIOUS chain:
    // G_base = 4*b7 + 8*b8 + 16*(b&127). Lanes: u0=c0, u1=c10, u2..u7=d0..d5;
    // regs r = (d6,d7,d8). 4 consecutive lanes = one 32B chunk.
    unsigned gb = 4u * ((b >> 7) & 1u) + 8u * ((b >> 8) & 1u) + 16u * (b & 127u);
    unsigned ubase = gb + (t & 1u) + 2u * ((t >> 1) & 1u) + (((t >> 2) & 63u) << 11);
    float2 w[8];
#pragma unroll
    for (int r = 0; r < 8; r++)
      w[r] = ld_amp(in, ubase + ((r & 1u) << 17) + (((r >> 1) & 1u) << 18) +
                            (((unsigned)r >> 2) << 19));
    // LDS scatter into tile order l' = c10 + 2*(d0..d8) + 1024*c0
    unsigned lbase = ((t >> 1) & 1u) + (((t >> 2) & 63u) << 1) + ((t & 1u) << 10);
#pragma unroll
    for (int r = 0; r < 8; r++) B[PHYS(lbase + ((unsigned)r << 7))] = w[r];
    __syncthreads();
    rot_load(B, t, v);  // v[m] = tile[8t+m]
  }

  if (TYPE == 0) phase<0, 1, 2, 0, 1>(v, MU, MC);      else phase<-1, 11, 12, 10, 11>(v, MU, MC);
  rot_store(A, t, v); __syncthreads(); rot_load(A, t, v);
  if (TYPE == 0) phase<-1, 3, 4, 2, 3>(v, MU, MC);     else phase<-1, 13, 14, 12, 13>(v, MU, MC);
  rot_store(B, t, v); __syncthreads(); rot_load(B, t, v);
  if (TYPE == 0) phase<-1, 5, 6, 4, 5>(v, MU, MC);     else phase<-1, 15, 16, 14, 15>(v, MU, MC);
  rot_store(A, t, v); __syncthreads(); rot_load(A, t, v);
  if (TYPE == 0) phase<-1, 7, 8, 6, 7>(v, MU, MC);     else phase<-1, 17, 18, 16, 17>(v, MU, MC);
  rot_store(B, t, v); __syncthreads(); rot_load(B, t, v);
  if (TYPE == 0) phase<-1, 9, 10, 8, 9>(v, MU, MC);    else phase<-1, 19, -1, 18, 19>(v, MU, MC);

  if (!FINAL) {
    // Dense store: regs j=(c8,c9,c10), lanes t=(c0..c7).
    // G = t0 + 2*j2 + 4*j0 + 8*j1 + 16*(t>>1) + (b<<11): 128B line per
    // lane-pair x 8 regs; wave covers 4KB.
    unsigned sbase = (b << 11) + (t & 1u) + (((t >> 1)) << 4);
#pragma unroll
    for (int j = 0; j < 8; j++) {
      unsigned off = 2u * ((j >> 2) & 1u) + 4u * (j & 1u) + 8u * ((j >> 1) & 1u);
      st_amp(outPsi, sbase + off, v[j]);
    }
  } else {
    // S2(2) end: m=(q18,q19,q0), t=(q10..q17), blk=(q1..q9).
    // Reference R (bit 19-q): R = m1 + 2*m0 + 4*rev8(t) + 1024*rev9(b) + 2^19*m2
    float xv[8];
    float s = 0.f;
#pragma unroll
    for (int m = 0; m < 8; m++) { xv[m] = xval(v[m]); s += xv[m]; }
#pragma unroll
    for (int o = 32; o > 0; o >>= 1) s += __shfl_down(s, o);
    if ((t & 63u) == 0) red[t >> 6] = s;
    __syncthreads();
    if (t == 0)
      __hip_atomic_store(&sumArr[b], red[0] + red[1] + red[2] + red[3],
                         __ATOMIC_RELAXED, __HIP_MEMORY_SCOPE_AGENT);
    gridbar(flags, 5, b, t);
    float s2 = __hip_atomic_load(&sumArr[2 * t], __ATOMIC_RELAXED,
                                 __HIP_MEMORY_SCOPE_AGENT) +
               __hip_atomic_load(&sumArr[2 * t + 1], __ATOMIC_RELAXED,
                                 __HIP_MEMORY_SCOPE_AGENT);
#pragma unroll
    for (int o = 32; o > 0; o >>= 1) s2 += __shfl_down(s2, o);
    __syncthreads();  // red reuse
    if ((t & 63u) == 0) red[t >> 6] = s2;
    __syncthreads();
    float mean = (red[0] + red[1] + red[2] + red[3]) * (1.f / 1048576.f);
    float4* o4 = (float4*)out;
    unsigned base = (__brev(t) >> 24) + ((__brev(b) >> 23) << 8);
    o4[base] = make_float4(xv[0] - mean, xv[2] - mean, xv[1] - mean, xv[3] - mean);
    o4[base + (1u << 17)] =
        make_float4(xv[4] - mean, xv[6] - mean, xv[5] - mean, xv[7] - mean);
  }
}

__global__ __launch_bounds__(NT) void qsim(const float* __restrict__ u3p,
                                           const float* __restrict__ cu3p,
                                           u64* __restrict__ psiA,
                                           u64* __restrict__ psiB,
                                           unsigned* __restrict__ flags,
                                           float* __restrict__ sumArr,
                                           float* __restrict__ out) {
  __shared__ float2 A[2304], B[2304];  // PHYS(2047)=2301
  __shared__ float2 Mall[480];         // 3 layers x (20 U3 + 20 CU3) x 4
  __shared__ float red[4];
  unsigned t = threadIdx.x, b = blockIdx.x;

  if (t < 60) mat_from(u3p + 3 * t, Mall + 4 * t);
  else if (t >= 64 && t < 124) mat_from(cu3p + 3 * (t - 64), Mall + 240 + 4 * (t - 64));
  __syncthreads();

  do_pass<0, 1, 0>(0, nullptr, psiB, A, B, Mall, red, t, b, sumArr, flags, out);
  gridbar(flags, 0, b, t);
  do_pass<1, 0, 0>(0, psiB, psiA, A, B, Mall, red, t, b, sumArr, flags, out);
  gridbar(flags, 1, b, t);
  do_pass<0, 0, 0>(1, psiA, psiB, A, B, Mall, red, t, b, sumArr, flags, out);
  gridbar(flags, 2, b, t);
  do_pass<1, 0, 0>(1, psiB, psiA, A, B, Mall, red, t, b, sumArr, flags, out);
  gridbar(flags, 3, b, t);
  do_pass<0, 0, 0>(2, psiA, psiB, A, B, Mall, red, t, b, sumArr, flags, out);
  gridbar(flags, 4, b, t);
  do_pass<1, 0, 1>(2, psiB, nullptr, A, B, Mall, red, t, b, sumArr, flags, out);
}

extern "C" void kernel_launch(void* const* d_in, const int* in_sizes, int n_in,
                              void* d_out, int out_size, void* d_ws, size_t ws_size,
                              hipStream_t stream) {
  const float* u3p = (const float*)d_in[0];
  const float* cu3p = (const float*)d_in[1];
  float* out = (float*)d_out;

  char* ws = (char*)d_ws;
  u64* psiA = (u64*)ws;                                         // 8 MB
  u64* psiB = (u64*)(ws + (size_t)8 * 1024 * 1024);             // 8 MB
  unsigned* flags = (unsigned*)(ws + (size_t)16 * 1024 * 1024); // 12 KB
  float* sumArr = (float*)(ws + (size_t)16 * 1024 * 1024 + 6 * NB * sizeof(unsigned));

  qsim<<<NB, NT, 0, stream>>>(u3p, cu3p, psiA, psiB, flags, sumArr, out);
}

// Round 11
// 174.030 us; speedup vs baseline: 1.3839x; 1.0931x over previous
//
#include <hip/hip_runtime.h>
#include <cstdint>
#include <cstddef>

// 20-qubit statevector sim, ONE kernel: 6 passes (2 per layer), fence-free
// flag grid barriers (R8-proven), 512 blocks x 256 threads.
//
// R9 post-mortem: exchange used 8B sc1 ops (16/thread/hop) -> LLC op-bound,
// and producer 8B stores half-filled HBM sectors (WRITE 86MB vs 44 useful).
// R10/R11 exchange layout (chain labels: c0..c10 = pass window in ring
// order, d0..d8 = external qubits in block-bit order), float2 index:
//   G = c10 + 2*c0 + 4*(c1..c7) + 512*c8 + 1024*c9 + 2048*(d0..d8)
// Producer regs j=(c8,c9,c10), lanes t=(c0..c7): float4 pairs over c10,
// 4 dwordx4-sc1 stores/thread; per instruction a wave covers a CONTIGUOUS
// 1KB run (addr = 2t + const) -> full sector fill, 1x write amp.
// Consumer (next window (c10,d0..d8,c0), block (c1..c9)): 4 dwordx4-sc1
// loads/thread (16B chunks, LLC-served), LDS scatter to tile order, then the
// R5-verified rotation-phase machinery runs unchanged.
// Hop symmetry S1->S2->S1 verified label-by-label; INIT/FINAL unchanged.
// R10 compile fix: inline asm needs first-class vector types
// (ext_vector_type), not HIP's float4 struct ("indirect register inputs").
//
// Phases: window always tile bits (0,1,2); tile rotates down by 2 between
// phases via LDS A/B double buffer, all b128. After 4 rotations regs hold
// m=(w8,w9,w10), t=(w0..w7). Final pass: x=(0.8*tanh(0.1*2^19*p))^0.3,
// block sums -> barrier -> mean -> bit-reversed scatter of x-mean to out.

#define NB 512
#define NT 256
#define MAGIC 0x13572468u
#define PHYS(L) ((L) + 2u * ((L) >> 4))

typedef float vf4 __attribute__((ext_vector_type(4)));

__device__ __forceinline__ void stf_sc1(float* p, float v) {
  __hip_atomic_store(p, v, __ATOMIC_RELAXED, __HIP_MEMORY_SCOPE_AGENT);
}
__device__ __forceinline__ float ldf_sc1(const float* p) {
  return __hip_atomic_load(p, __ATOMIC_RELAXED, __HIP_MEMORY_SCOPE_AGENT);
}

__device__ __forceinline__ float2 cmadd2(float2 m0, float2 a0, float2 m1, float2 a1) {
  float2 r;
  r.x = m0.x * a0.x - m0.y * a0.y + m1.x * a1.x - m1.y * a1.y;
  r.y = m0.x * a0.y + m0.y * a0.x + m1.x * a1.y + m1.y * a1.x;
  return r;
}

template <int BIT>
__device__ __forceinline__ void applyU3(float2* v, const float2* m) {
  float2 m00 = m[0], m01 = m[1], m10 = m[2], m11 = m[3];
#pragma unroll
  for (int j = 0; j < 8; j++)
    if (!((j >> BIT) & 1)) {
      int j1 = j | (1 << BIT);
      float2 a0 = v[j], a1 = v[j1];
      v[j] = cmadd2(m00, a0, m01, a1);
      v[j1] = cmadd2(m10, a0, m11, a1);
    }
}

template <int C, int T>
__device__ __forceinline__ void applyCU3(float2* v, const float2* m) {
  float2 u00 = m[0], u01 = m[1], u10 = m[2], u11 = m[3];
#pragma unroll
  for (int j = 0; j < 8; j++)
    if (((j >> C) & 1) && !((j >> T) & 1)) {
      int j1 = j | (1 << T);
      float2 a0 = v[j], a1 = v[j1];
      v[j] = cmadd2(u00, a0, u01, a1);
      v[j1] = cmadd2(u10, a0, u11, a1);
    }
}

template <int U0, int U1, int U2, int C01, int C12>
__device__ __forceinline__ void phase(float2* v, const float2* MU, const float2* MC) {
  if (U0 >= 0) applyU3<0>(v, MU + 4 * (U0 < 0 ? 0 : U0));
  if (U1 >= 0) applyU3<1>(v, MU + 4 * (U1 < 0 ? 0 : U1));
  if (U2 >= 0) applyU3<2>(v, MU + 4 * (U2 < 0 ? 0 : U2));
  if (C01 >= 0) applyCU3<0, 1>(v, MC + 4 * (C01 < 0 ? 0 : C01));
  if (C12 >= 0) applyCU3<1, 2>(v, MC + 4 * (C12 < 0 ? 0 : C12));
}

__device__ __forceinline__ void rot_store(float2* lds, unsigned t, const float2* v) {
#pragma unroll
  for (int q = 0; q < 4; q++) {
    unsigned Lp = 2u * t + 512u * q;
    vf4 val = {v[q].x, v[q].y, v[q + 4].x, v[q + 4].y};
    *(vf4*)&lds[PHYS(Lp)] = val;
  }
}

__device__ __forceinline__ void rot_load(const float2* lds, unsigned t, float2* v) {
  const vf4* p = (const vf4*)&lds[PHYS(8u * t)];
#pragma unroll
  for (int i = 0; i < 4; i++) {
    vf4 f = p[i];
    v[2 * i] = make_float2(f.x, f.y);
    v[2 * i + 1] = make_float2(f.z, f.w);
  }
}

__device__ __forceinline__ float xval(float2 a) {
  float p = a.x * a.x + a.y * a.y;
  return powf(0.8f * tanhf(52428.8f * p), 0.3f);
}

__device__ __forceinline__ void mat_from(const float* s, float2* m) {
  float st, ct, sl, cl, sp, cp, spl, cpl;
  sincosf(0.5f * s[0], &st, &ct);
  sincosf(s[2], &sl, &cl);
  sincosf(s[1], &sp, &cp);
  sincosf(s[1] + s[2], &spl, &cpl);
  m[0] = make_float2(ct, 0.f);
  m[1] = make_float2(-cl * st, -sl * st);
  m[2] = make_float2(cp * st, sp * st);
  m[3] = make_float2(cpl * ct, spl * ct);
}

// Fence-free grid barrier (R8-proven). Explicit vmcnt drain first: the
// exchange stores are inline asm the compiler does not track.
__device__ __forceinline__ void gridbar(unsigned* flags, int slot, unsigned b,
                                        unsigned t) {
  asm volatile("s_waitcnt vmcnt(0)" ::: "memory");
  __syncthreads();
  unsigned* base = flags + slot * NB;
  if (t == 0)
    __hip_atomic_store(base + b, MAGIC, __ATOMIC_RELAXED, __HIP_MEMORY_SCOPE_AGENT);
  if (t < 64) {
    unsigned* p = base + 8 * t;
    int guard = 0;
    for (;;) {
      unsigned ok = 1u;
#pragma unroll
      for (int i = 0; i < 8; i++)
        ok &= (__hip_atomic_load(p + i, __ATOMIC_RELAXED,
                                 __HIP_MEMORY_SCOPE_AGENT) == MAGIC);
      if (__all((int)ok)) break;
      if (++guard > (1 << 18)) break;  // fail loud, never hang
      __builtin_amdgcn_s_sleep(8);
    }
  }
  __syncthreads();
}

// TYPE 0 = S1, 1 = S2; INIT synthesizes |0..0>; FINAL does readout.
template <int TYPE, int INIT, int FINAL>
__device__ __forceinline__ void do_pass(int k, const float2* in, float2* outPsi,
                                        float2* A, float2* B, const float2* Mall,
                                        float* red, unsigned t, unsigned b,
                                        float* sumArr, unsigned* flags,
                                        float* out) {
  const float2* MU = Mall + k * 80;
  const float2* MC = Mall + 240 + k * 80;

  float2 v[8];
  if (INIT) {
#pragma unroll
    for (int j = 0; j < 8; j++) v[j] = make_float2(0.f, 0.f);
    if (b == 0 && t == 0) v[0] = make_float2(1.f, 0.f);
  } else {
    // Gather: b = (c1..c9) of producer chain.
    // gb = 4*(b&127) + 512*b7 + 1024*b8; float4 chunk (l0 pair) at
    // addr = gb + 2*l10 + 2048*(l1..l9): l10 = t&1, (l1..l7) = t>>1,
    // (l8,l9) = reg r (strides 2^18, 2^19).
    unsigned gb = 4u * (b & 127u) + 512u * ((b >> 7) & 1u) + 1024u * ((b >> 8) & 1u);
    const float2* p0 = in + gb + 2u * (t & 1u) + 2048u * (t >> 1);
    const float2* p1 = p0 + (1u << 18);
    const float2* p2 = p0 + (2u << 18);
    const float2* p3 = p0 + (3u << 18);
    vf4 w0, w1, w2, w3;
    asm volatile(
        "global_load_dwordx4 %0, %4, off sc1\n\t"
        "global_load_dwordx4 %1, %5, off sc1\n\t"
        "global_load_dwordx4 %2, %6, off sc1\n\t"
        "global_load_dwordx4 %3, %7, off sc1\n\t"
        "s_waitcnt vmcnt(0)"
        : "=&v"(w0), "=&v"(w1), "=&v"(w2), "=&v"(w3)
        : "v"(p0), "v"(p1), "v"(p2), "v"(p3)
        : "memory");
    // LDS scatter to tile order: lp = 2*(t>>1) + 1024*(t&1) + 256*(r&1)
    // + 512*(r>>1); float4 covers tile bit0 (l0).
    unsigned lp = 2u * (t >> 1) + 1024u * (t & 1u);
    *(vf4*)&B[PHYS(lp)] = w0;
    *(vf4*)&B[PHYS(lp + 256u)] = w1;
    *(vf4*)&B[PHYS(lp + 512u)] = w2;
    *(vf4*)&B[PHYS(lp + 768u)] = w3;
    __syncthreads();
    rot_load(B, t, v);
  }

  if (TYPE == 0) phase<0, 1, 2, 0, 1>(v, MU, MC);      else phase<-1, 11, 12, 10, 11>(v, MU, MC);
  rot_store(A, t, v); __syncthreads(); rot_load(A, t, v);
  if (TYPE == 0) phase<-1, 3, 4, 2, 3>(v, MU, MC);     else phase<-1, 13, 14, 12, 13>(v, MU, MC);
  rot_store(B, t, v); __syncthreads(); rot_load(B, t, v);
  if (TYPE == 0) phase<-1, 5, 6, 4, 5>(v, MU, MC);     else phase<-1, 15, 16, 14, 15>(v, MU, MC);
  rot_store(A, t, v); __syncthreads(); rot_load(A, t, v);
  if (TYPE == 0) phase<-1, 7, 8, 6, 7>(v, MU, MC);     else phase<-1, 17, 18, 16, 17>(v, MU, MC);
  rot_store(B, t, v); __syncthreads(); rot_load(B, t, v);
  if (TYPE == 0) phase<-1, 9, 10, 8, 9>(v, MU, MC);    else phase<-1, 19, -1, 18, 19>(v, MU, MC);

  if (!FINAL) {
    // Dense store: regs j=(c8,c9,c10), lanes t=(c0..c7).
    // addr = 2t + 512*(rr&1) + 1024*(rr>>1) + (b<<11); float4 pairs over c10
    // (G bit0). Per instruction a wave covers contiguous 1KB.
    float2* o = outPsi + ((size_t)b << 11) + 2u * t;
#pragma unroll
    for (int rr = 0; rr < 4; rr++) {
      vf4 val = {v[rr].x, v[rr].y, v[rr + 4].x, v[rr + 4].y};
      float2* addr = o + 512u * (rr & 1) + 1024u * (rr >> 1);
      asm volatile("global_store_dwordx4 %0, %1, off sc1" ::"v"(addr), "v"(val)
                   : "memory");
    }
  } else {
    // S2(2) end: m=(q18,q19,q0), t=(q10..q17), blk=(q1..q9).
    // Reference R (bit 19-q): R = m1 + 2*m0 + 4*rev8(t) + 1024*rev9(b) + 2^19*m2
    float xv[8];
    float s = 0.f;
#pragma unroll
    for (int m = 0; m < 8; m++) { xv[m] = xval(v[m]); s += xv[m]; }
#pragma unroll
    for (int o = 32; o > 0; o >>= 1) s += __shfl_down(s, o);
    if ((t & 63u) == 0) red[t >> 6] = s;
    __syncthreads();
    if (t == 0) stf_sc1(&sumArr[b], red[0] + red[1] + red[2] + red[3]);
    gridbar(flags, 5, b, t);
    float s2 = ldf_sc1(&sumArr[2 * t]) + ldf_sc1(&sumArr[2 * t + 1]);
#pragma unroll
    for (int o = 32; o > 0; o >>= 1) s2 += __shfl_down(s2, o);
    __syncthreads();  // red reuse
    if ((t & 63u) == 0) red[t >> 6] = s2;
    __syncthreads();
    float mean = (red[0] + red[1] + red[2] + red[3]) * (1.f / 1048576.f);
    float4* o4 = (float4*)out;
    unsigned base = (__brev(t) >> 24) + ((__brev(b) >> 23) << 8);
    o4[base] = make_float4(xv[0] - mean, xv[2] - mean, xv[1] - mean, xv[3] - mean);
    o4[base + (1u << 17)] =
        make_float4(xv[4] - mean, xv[6] - mean, xv[5] - mean, xv[7] - mean);
  }
}

__global__ __launch_bounds__(NT) void qsim(const float* __restrict__ u3p,
                                           const float* __restrict__ cu3p,
                                           float2* __restrict__ psiA,
                                           float2* __restrict__ psiB,
                                           unsigned* __restrict__ flags,
                                           float* __restrict__ sumArr,
                                           float* __restrict__ out) {
  __shared__ __align__(16) float2 A[2304], B[2304];  // PHYS(2047)=2301
  __shared__ float2 Mall[480];  // 3 layers x (20 U3 + 20 CU3) x 4
  __shared__ float red[4];
  unsigned t = threadIdx.x, b = blockIdx.x;

  if (t < 60) mat_from(u3p + 3 * t, Mall + 4 * t);
  else if (t >= 64 && t < 124) mat_from(cu3p + 3 * (t - 64), Mall + 240 + 4 * (t - 64));
  __syncthreads();

  do_pass<0, 1, 0>(0, nullptr, psiB, A, B, Mall, red, t, b, sumArr, flags, out);
  gridbar(flags, 0, b, t);
  do_pass<1, 0, 0>(0, psiB, psiA, A, B, Mall, red, t, b, sumArr, flags, out);
  gridbar(flags, 1, b, t);
  do_pass<0, 0, 0>(1, psiA, psiB, A, B, Mall, red, t, b, sumArr, flags, out);
  gridbar(flags, 2, b, t);
  do_pass<1, 0, 0>(1, psiB, psiA, A, B, Mall, red, t, b, sumArr, flags, out);
  gridbar(flags, 3, b, t);
  do_pass<0, 0, 0>(2, psiA, psiB, A, B, Mall, red, t, b, sumArr, flags, out);
  gridbar(flags, 4, b, t);
  do_pass<1, 0, 1>(2, psiB, nullptr, A, B, Mall, red, t, b, sumArr, flags, out);
}

extern "C" void kernel_launch(void* const* d_in, const int* in_sizes, int n_in,
                              void* d_out, int out_size, void* d_ws, size_t ws_size,
                              hipStream_t stream) {
  const float* u3p = (const float*)d_in[0];
  const float* cu3p = (const float*)d_in[1];
  float* out = (float*)d_out;

  char* ws = (char*)d_ws;
  float2* psiA = (float2*)ws;                                   // 8 MB
  float2* psiB = (float2*)(ws + (size_t)8 * 1024 * 1024);       // 8 MB
  unsigned* flags = (unsigned*)(ws + (size_t)16 * 1024 * 1024); // 12 KB
  float* sumArr = (float*)(ws + (size_t)16 * 1024 * 1024 + 6 * NB * sizeof(unsigned));

  qsim<<<NB, NT, 0, stream>>>(u3p, cu3p, psiA, psiB, flags, sumArr, out);
}